// Round 1
// baseline (801.663 us; speedup 1.0000x reference)
//
#include <hip/hip_runtime.h>

// LIF SNN benchmark: cur = X @ W^T (fp64 accumulate), then LIF scan over T.
// T=256, B=64, F=1024. M = T*B = 16384, N = K = 1024.
// Correctness-first baseline: fp64 GEMM accumulation + fp64 scan state to make
// spike decisions match the true real-arithmetic result as closely as possible
// (output is binary; one flipped spike = absmax 1.0 = fail).

#define M_DIM 16384
#define N_DIM 1024
#define K_DIM 1024
#define PLANE 65536   // B*F = 64*1024
#define T_STEPS 256

// ---------------------------------------------------------------------------
// Kernel A: cur[m][n] = sum_k X[m][k] * W[n][k], fp64 accumulate, f32 store.
// 64x64 output tile, BK=64, 256 threads, 4x4 fp64 acc per thread.
// LDS tiles stored k-major ([k][m], [k][n]) with row stride 68 floats:
//   - 68*4 = 272 B, 16-aligned -> float4 LDS reads legal
//   - read pattern per k: 16-lane b128 strips, <=2-way bank aliasing (free)
// ---------------------------------------------------------------------------
__global__ __launch_bounds__(256) void lif_gemm_fp64(
    const float* __restrict__ X, const float* __restrict__ W,
    float* __restrict__ out) {
    __shared__ float As[64][68];  // [k][m]
    __shared__ float Bs[64][68];  // [k][n]

    const int tid = threadIdx.x;
    const int bn  = blockIdx.x;   // 0..15   (n tiles)
    const int bm  = blockIdx.y;   // 0..255  (m tiles)
    const int tn4 = tid & 15;     // n sub-tile
    const int tm4 = tid >> 4;     // m sub-tile

    double acc[4][4] = {};

    // loader mapping: 256 threads load 64 rows x 16 float4 (per matrix)
    const int lrow = tid >> 2;    // 0..63 : row within tile (m or n)
    const int lc4  = tid & 3;     // 0..3  : float4 column group
    const float* Abase = X + (size_t)(bm * 64 + lrow) * K_DIM;
    const float* Bbase = W + (size_t)(bn * 64 + lrow) * K_DIM;

    for (int k0 = 0; k0 < K_DIM; k0 += 64) {
        #pragma unroll
        for (int j = 0; j < 4; ++j) {
            const int c = lc4 + 4 * j;  // float4 index within the 64-wide k tile
            float4 a = *reinterpret_cast<const float4*>(Abase + k0 + 4 * c);
            float4 b = *reinterpret_cast<const float4*>(Bbase + k0 + 4 * c);
            As[4*c+0][lrow] = a.x; As[4*c+1][lrow] = a.y;
            As[4*c+2][lrow] = a.z; As[4*c+3][lrow] = a.w;
            Bs[4*c+0][lrow] = b.x; Bs[4*c+1][lrow] = b.y;
            Bs[4*c+2][lrow] = b.z; Bs[4*c+3][lrow] = b.w;
        }
        __syncthreads();

        #pragma unroll 8
        for (int k = 0; k < 64; ++k) {
            float4 a4 = *reinterpret_cast<const float4*>(&As[k][tm4 * 4]);
            float4 b4 = *reinterpret_cast<const float4*>(&Bs[k][tn4 * 4]);
            const double ad[4] = {(double)a4.x, (double)a4.y, (double)a4.z, (double)a4.w};
            const double bd[4] = {(double)b4.x, (double)b4.y, (double)b4.z, (double)b4.w};
            #pragma unroll
            for (int i = 0; i < 4; ++i)
                #pragma unroll
                for (int j = 0; j < 4; ++j)
                    acc[i][j] = fma(ad[i], bd[j], acc[i][j]);
        }
        __syncthreads();
    }

    #pragma unroll
    for (int i = 0; i < 4; ++i) {
        const int m = bm * 64 + tm4 * 4 + i;
        float4 o;
        o.x = (float)acc[i][0];
        o.y = (float)acc[i][1];
        o.z = (float)acc[i][2];
        o.w = (float)acc[i][3];
        *reinterpret_cast<float4*>(out + (size_t)m * N_DIM + bn * 64 + tn4 * 4) = o;
    }
}

// ---------------------------------------------------------------------------
// Kernel B: in-place LIF scan over T on d_out.
// Each thread owns one (b, g) pair; reads cur[t] (f32), fp64 state update:
//   v = v + (c - v) / 2 ; spike = (v - 1 >= 0) ; v = spike ? 0 : v
// Reads each element exactly once before overwriting it with the spike.
// ---------------------------------------------------------------------------
__global__ __launch_bounds__(256) void lif_scan_fp64(float* __restrict__ buf) {
    const int gid = blockIdx.x * 256 + threadIdx.x;  // 0..65535
    double v = 0.0;
    #pragma unroll 4
    for (int t = 0; t < T_STEPS; ++t) {
        float* p = buf + (size_t)t * PLANE + gid;
        const double c = (double)(*p);
        v = v + (c - v) * 0.5;               // (x - v)/tau, tau = 2 (exact *0.5)
        const bool spike = (v - 1.0 >= 0.0); // v_threshold = 1.0
        *p = spike ? 1.0f : 0.0f;
        v = spike ? 0.0 : v;
    }
}

extern "C" void kernel_launch(void* const* d_in, const int* in_sizes, int n_in,
                              void* d_out, int out_size, void* d_ws, size_t ws_size,
                              hipStream_t stream) {
    const float* X = (const float*)d_in[0];  // [T,B,F] binary spikes, fp32
    const float* W = (const float*)d_in[1];  // [F,F] weights, fp32
    float* out = (float*)d_out;              // [T,B,F] fp32

    dim3 grid(N_DIM / 64, M_DIM / 64);       // (16, 256)
    lif_gemm_fp64<<<grid, 256, 0, stream>>>(X, W, out);
    lif_scan_fp64<<<PLANE / 256, 256, 0, stream>>>(out);
}

// Round 2
// 197.531 us; speedup vs baseline: 4.0584x; 4.0584x over previous
//
#include <hip/hip_runtime.h>
#include <stdint.h>

// LIF SNN: cur = X @ W^T then LIF scan. T=256,B=64,F=1024 -> M=16384,N=K=1024.
// Fast path: EXACT integer GEMM. W quantized at 2^-35 (exact for |W|>=2^-12;
// error <=2^-36 on the rare tiny elements -> ~1e-10 per dot product, far below
// decision margins). k=rint(W*2^35) (|k|<=2^30) split into 4 signed i8 limbs,
// 4 limb-GEMMs on mfma_i32_32x32x32_i8 (i32 acc exact, |s|<=2^17), combined in
// fp64 (exact) and rounded once to f32 — matches round-1's exact fp64 result.
// Fallback (ws too small): round-1 fp64 GEMM (proven absmax 0.0).

#define T_STEPS 256
#define M_DIM 16384
#define N_DIM 1024
#define K_DIM 1024
#define PLANE 65536   // B*F

typedef int v4i  __attribute__((ext_vector_type(4)));
typedef int v16i __attribute__((ext_vector_type(16)));
typedef unsigned int u32;

#define WS_BITS_SZ  (M_DIM * 128)                 // X as bits: 2 MB
#define WS_LIMB_OFF WS_BITS_SZ                    // 4 i8 planes x 1 MB
#define WS_NEEDED   (WS_BITS_SZ + 4 * (1 << 20))  // 6 MB

__device__ __forceinline__ void gload_lds16(const void* g, void* l) {
    __builtin_amdgcn_global_load_lds(
        (const __attribute__((address_space(1))) u32*)g,
        (__attribute__((address_space(3))) u32*)l, 16, 0, 0);
}

// ---------------- prep: pack X (0.0/1.0) into bits -------------------------
__global__ __launch_bounds__(256) void prep_bits(const float* __restrict__ X,
                                                 unsigned long long* __restrict__ bits) {
    const int gid = blockIdx.x * 256 + threadIdx.x;   // grid covers 16.7M
    const float x = X[gid];
    const unsigned long long m = __ballot(x != 0.0f);
    if ((threadIdx.x & 63) == 0) bits[gid >> 6] = m;
}

// ---------------- prep: W -> 4 signed i8 limb planes at scale 2^-35 --------
__global__ __launch_bounds__(256) void prep_limbs(const float* __restrict__ W,
                                                  char* __restrict__ limbs) {
    const int gid = blockIdx.x * 256 + threadIdx.x;   // 0..2^20-1
    const double d = (double)W[gid] * 34359738368.0;  // * 2^35, exact
    long long k = llrint(d);                          // |k| <= 2^30
    const int8_t l0 = (int8_t)k; k = (k - l0) >> 8;   // exact balanced digits
    const int8_t l1 = (int8_t)k; k = (k - l1) >> 8;
    const int8_t l2 = (int8_t)k; k = (k - l2) >> 8;
    const int8_t l3 = (int8_t)k;                      // |l3| <= 65
    limbs[gid]               = (char)l0;
    limbs[gid + (1 << 20)]   = (char)l1;
    limbs[gid + 2 * (1 << 20)] = (char)l2;
    limbs[gid + 3 * (1 << 20)] = (char)l3;
}

// ---------------- i8 MFMA GEMM --------------------------------------------
// Block: 512 thr = 8 waves (2 wave-rows x 4 wave-cols). Tile 128M x 128N,
// K-step 64. Wave: 2 m-tiles(32) x 1 n-tile(32) x 4 limbs -> acc 2*4*16 regs.
// LDS per K-step buffer: A 8 chunks(1KB) + B 32 chunks = 40KB, double buffered.
// Chunks are frag-linear (lane*16) -> conflict-free ds_read_b128.
#define LDSH 40960

__global__ __launch_bounds__(512, 2) void gemm_i8(
    const char* __restrict__ bits8, const char* __restrict__ limbs,
    float* __restrict__ out) {
    __shared__ __align__(16) char lds[2 * LDSH];   // 80 KB

    const int tid  = threadIdx.x;
    const int lane = tid & 63;
    const int w    = tid >> 6;        // 0..7
    const int wr   = w >> 2;          // 0..1
    const int wc   = w & 3;           // 0..3
    const int l31  = lane & 31;
    const int lh   = lane >> 5;       // k-half select
    const int bn   = blockIdx.x;      // 0..7
    const int bm   = blockIdx.y;      // 0..127

    v16i acc[2][4] = {};

    // A staging: wave w unpacks chunk (g = w>>1, ks = w&1).
    const int ag = w >> 1, aks = w & 1;
    // byte offset into bit matrix for this lane's 16 k-bits (before k0):
    const size_t a_bit_off =
        (size_t)(bm * 128 + ag * 32 + l31) * 128 + (size_t)(aks * 4 + lh * 2);
    const int a_lds_off = (ag * 2 + aks) * 1024 + lane * 16;

    // B staging: wave w DMAs chunks id = w*4 + j, j=0..3.
    size_t b_goff[4];
    int    b_loff[4];
    #pragma unroll
    for (int j = 0; j < 4; ++j) {
        const int id = w * 4 + j;
        const int c  = id >> 3, lb = (id >> 1) & 3, ks = id & 1;
        b_goff[j] = (size_t)lb * (1 << 20) +
                    (size_t)(bn * 128 + c * 32 + l31) * 1024 +
                    (size_t)(ks * 32 + lh * 16);
        b_loff[j] = 8192 + id * 1024;
    }

    // ---- prologue: stage k0 = 0 into buffer 0 ----
    {
        const int k0 = 0;
        #pragma unroll
        for (int j = 0; j < 4; ++j)
            gload_lds16(limbs + b_goff[j] + k0, lds + b_loff[j]);
        const unsigned short sb =
            *(const unsigned short*)(bits8 + a_bit_off + (k0 >> 3));
        v4i av;
        #pragma unroll
        for (int q = 0; q < 4; ++q) {
            const u32 x = ((u32)sb >> (4 * q)) & 0xF;
            av[q] = (int)((x & 1) | ((x & 2) << 7) | ((x & 4) << 14) | ((x & 8) << 21));
        }
        *(v4i*)(lds + a_lds_off) = av;
    }
    __syncthreads();

    for (int t = 0; t < 16; ++t) {
        const int p = t & 1;
        // stage next K-step into the other buffer
        if (t + 1 < 16) {
            const int k0 = (t + 1) * 64;
            #pragma unroll
            for (int j = 0; j < 4; ++j)
                gload_lds16(limbs + b_goff[j] + k0, lds + (p ^ 1) * LDSH + b_loff[j]);
            const unsigned short sb =
                *(const unsigned short*)(bits8 + a_bit_off + (k0 >> 3));
            v4i av;
            #pragma unroll
            for (int q = 0; q < 4; ++q) {
                const u32 x = ((u32)sb >> (4 * q)) & 0xF;
                av[q] = (int)((x & 1) | ((x & 2) << 7) | ((x & 4) << 14) | ((x & 8) << 21));
            }
            *(v4i*)(lds + (p ^ 1) * LDSH + a_lds_off) = av;
        }
        // compute current buffer
        const char* Ab = lds + p * LDSH;
        const char* Bb = Ab + 8192;
        #pragma unroll
        for (int ks = 0; ks < 2; ++ks) {
            const v4i a0 = *(const v4i*)(Ab + ((2 * wr) * 2 + ks) * 1024 + lane * 16);
            const v4i a1 = *(const v4i*)(Ab + ((2 * wr + 1) * 2 + ks) * 1024 + lane * 16);
            #pragma unroll
            for (int lb = 0; lb < 4; ++lb) {
                const v4i b = *(const v4i*)(Bb + ((wc * 4 + lb) * 2 + ks) * 1024 + lane * 16);
                acc[0][lb] = __builtin_amdgcn_mfma_i32_32x32x32_i8(a0, b, acc[0][lb], 0, 0, 0);
                acc[1][lb] = __builtin_amdgcn_mfma_i32_32x32x32_i8(a1, b, acc[1][lb], 0, 0, 0);
            }
        }
        __syncthreads();
    }

    // ---- epilogue: combine limbs in fp64 (exact) and store f32 ----
    #pragma unroll
    for (int i = 0; i < 2; ++i) {
        #pragma unroll
        for (int r = 0; r < 16; ++r) {
            const double s = (double)acc[i][0][r] + 256.0 * (double)acc[i][1][r] +
                             65536.0 * (double)acc[i][2][r] +
                             16777216.0 * (double)acc[i][3][r];
            const float cur = (float)(s * 2.9103830456733704e-11);  // * 2^-35
            const int row = (r & 3) + 8 * (r >> 2) + 4 * lh;
            const int m   = bm * 128 + (2 * wr + i) * 32 + row;
            const int n   = bn * 128 + wc * 32 + l31;
            out[(size_t)m * N_DIM + n] = cur;
        }
    }
}

// ---------------- LIF scan, fp64 state, depth-4 prefetch ring --------------
__global__ __launch_bounds__(256) void lif_scan2(float* __restrict__ buf) {
    const int gid = blockIdx.x * 256 + threadIdx.x;   // 0..65535
    float c[4];
    #pragma unroll
    for (int q = 0; q < 4; ++q) c[q] = buf[(size_t)q * PLANE + gid];
    double v = 0.0;
    for (int t = 0; t < T_STEPS; t += 4) {
        #pragma unroll
        for (int q = 0; q < 4; ++q) {
            const double cd = (double)c[q];
            v = v + (cd - v) * 0.5;
            const bool s = (v >= 1.0);
            buf[(size_t)(t + q) * PLANE + gid] = s ? 1.0f : 0.0f;
            v = s ? 0.0 : v;
            const int tn = t + q + 4;
            c[q] = (tn < T_STEPS) ? buf[(size_t)tn * PLANE + gid] : 0.0f;
        }
    }
}

// ---------------- fallback: round-1 fp64 GEMM (proven) ---------------------
__global__ __launch_bounds__(256) void lif_gemm_fp64(
    const float* __restrict__ X, const float* __restrict__ W,
    float* __restrict__ out) {
    __shared__ float As[64][68];
    __shared__ float Bs[64][68];
    const int tid = threadIdx.x;
    const int bn = blockIdx.x, bm = blockIdx.y;
    const int tn4 = tid & 15, tm4 = tid >> 4;
    double acc[4][4] = {};
    const int lrow = tid >> 2, lc4 = tid & 3;
    const float* Abase = X + (size_t)(bm * 64 + lrow) * K_DIM;
    const float* Bbase = W + (size_t)(bn * 64 + lrow) * K_DIM;
    for (int k0 = 0; k0 < K_DIM; k0 += 64) {
        #pragma unroll
        for (int j = 0; j < 4; ++j) {
            const int c = lc4 + 4 * j;
            float4 a = *reinterpret_cast<const float4*>(Abase + k0 + 4 * c);
            float4 b = *reinterpret_cast<const float4*>(Bbase + k0 + 4 * c);
            As[4*c+0][lrow] = a.x; As[4*c+1][lrow] = a.y;
            As[4*c+2][lrow] = a.z; As[4*c+3][lrow] = a.w;
            Bs[4*c+0][lrow] = b.x; Bs[4*c+1][lrow] = b.y;
            Bs[4*c+2][lrow] = b.z; Bs[4*c+3][lrow] = b.w;
        }
        __syncthreads();
        #pragma unroll 8
        for (int k = 0; k < 64; ++k) {
            float4 a4 = *reinterpret_cast<const float4*>(&As[k][tm4 * 4]);
            float4 b4 = *reinterpret_cast<const float4*>(&Bs[k][tn4 * 4]);
            const double ad[4] = {(double)a4.x, (double)a4.y, (double)a4.z, (double)a4.w};
            const double bd[4] = {(double)b4.x, (double)b4.y, (double)b4.z, (double)b4.w};
            #pragma unroll
            for (int i = 0; i < 4; ++i)
                #pragma unroll
                for (int j = 0; j < 4; ++j)
                    acc[i][j] = fma(ad[i], bd[j], acc[i][j]);
        }
        __syncthreads();
    }
    #pragma unroll
    for (int i = 0; i < 4; ++i) {
        const int m = bm * 64 + tm4 * 4 + i;
        float4 o;
        o.x = (float)acc[i][0]; o.y = (float)acc[i][1];
        o.z = (float)acc[i][2]; o.w = (float)acc[i][3];
        *reinterpret_cast<float4*>(out + (size_t)m * N_DIM + bn * 64 + tn4 * 4) = o;
    }
}

extern "C" void kernel_launch(void* const* d_in, const int* in_sizes, int n_in,
                              void* d_out, int out_size, void* d_ws, size_t ws_size,
                              hipStream_t stream) {
    const float* X = (const float*)d_in[0];
    const float* W = (const float*)d_in[1];
    float* out = (float*)d_out;

    if (ws_size >= (size_t)WS_NEEDED) {
        char* ws = (char*)d_ws;
        unsigned long long* bits = (unsigned long long*)ws;
        char* limbs = ws + WS_LIMB_OFF;
        prep_bits<<<M_DIM * K_DIM / 256, 256, 0, stream>>>(X, bits);
        prep_limbs<<<N_DIM * K_DIM / 256, 256, 0, stream>>>(W, limbs);
        dim3 grid(N_DIM / 128, M_DIM / 128);   // (8, 128)
        gemm_i8<<<grid, 512, 0, stream>>>((const char*)ws, limbs, out);
    } else {
        dim3 grid(N_DIM / 64, M_DIM / 64);
        lif_gemm_fp64<<<grid, 256, 0, stream>>>(X, W, out);
    }
    lif_scan2<<<PLANE / 256, 256, 0, stream>>>(out);
}

// Round 3
// 135.845 us; speedup vs baseline: 5.9013x; 1.4541x over previous
//
#include <hip/hip_runtime.h>
#include <stdint.h>

// LIF SNN: cur = X @ W^T then LIF scan. T=256,B=64,F=1024 -> M=16384,N=K=1024.
// EXACT integer GEMM: W quantized at 2^-35 -> 4 signed i8 limbs,
// mfma_i32_32x32x32_i8 (exact i32 acc), fp64 limb combine (exact), one f32
// rounding -> decision-identical to exact fp64 (absmax 0.0 in rounds 1+2).
//
// Round-3 structure: block = 8 independent waves sharing one 32-col B panel.
// B staged in 2x32KB LDS halves (4 K-steps x 4 limbs each) -> 5 barriers per
// block total (vs 17), each preceded by ~4700 cyc of MFMA so the vmcnt drain
// is covered. A unpacked per-wave from the bit matrix in registers (no
// staging). Wave tile 64m x 32n x 4 limbs.

#define T_STEPS 256
#define M_DIM 16384
#define N_DIM 1024
#define K_DIM 1024
#define PLANE 65536   // B*F

typedef int v4i  __attribute__((ext_vector_type(4)));
typedef int v16i __attribute__((ext_vector_type(16)));
typedef unsigned int u32;
typedef unsigned long long u64;

#define WS_BITS_SZ  (M_DIM * 128)                 // X as bits: 2 MB
#define WS_LIMB_OFF WS_BITS_SZ                    // 4 i8 planes x 1 MB
#define WS_NEEDED   (WS_BITS_SZ + 4 * (1 << 20))  // 6 MB

__device__ __forceinline__ void gload_lds16(const void* g, void* l) {
    __builtin_amdgcn_global_load_lds(
        (const __attribute__((address_space(1))) u32*)g,
        (__attribute__((address_space(3))) u32*)l, 16, 0, 0);
}

// expand 16 k-bits into 16 i8 bytes (0/1) packed in 4 u32 (verified layout r2)
__device__ __forceinline__ v4i expand16(u32 sb) {
    v4i r;
    #pragma unroll
    for (int q = 0; q < 4; ++q) {
        const u32 x = (sb >> (4 * q)) & 0xF;
        r[q] = (int)((x & 1) | ((x & 2) << 7) | ((x & 4) << 14) | ((x & 8) << 21));
    }
    return r;
}

// ---------------- prep: pack X (0.0/1.0) into bits -------------------------
__global__ __launch_bounds__(256) void prep_bits(const float* __restrict__ X,
                                                 u64* __restrict__ bits) {
    const int gid = blockIdx.x * 256 + threadIdx.x;
    const float x = X[gid];
    const u64 m = __ballot(x != 0.0f);
    if ((threadIdx.x & 63) == 0) bits[gid >> 6] = m;
}

// ---------------- prep: W -> 4 signed i8 limb planes at scale 2^-35 --------
__global__ __launch_bounds__(256) void prep_limbs(const float* __restrict__ W,
                                                  char* __restrict__ limbs) {
    const int gid = blockIdx.x * 256 + threadIdx.x;   // 0..2^20-1
    const double d = (double)W[gid] * 34359738368.0;  // * 2^35, exact
    long long k = llrint(d);                          // |k| <= 2^30
    const int8_t l0 = (int8_t)k; k = (k - l0) >> 8;   // exact balanced digits
    const int8_t l1 = (int8_t)k; k = (k - l1) >> 8;
    const int8_t l2 = (int8_t)k; k = (k - l2) >> 8;
    const int8_t l3 = (int8_t)k;
    limbs[gid]                 = (char)l0;
    limbs[gid + (1 << 20)]     = (char)l1;
    limbs[gid + 2 * (1 << 20)] = (char)l2;
    limbs[gid + 3 * (1 << 20)] = (char)l3;
}

// ---------------- i8 MFMA GEMM, register-A / LDS-B panel -------------------
// Grid (32 n-panels, 32 m-panels). Block: 512 thr = 8 waves, each wave owns
// 64 m-rows (2 x 32) of the block's 512-row panel; all share 32 n-cols.
// LDS: 2 half-K buffers of 32KB = [kk 0..3][lb 0..3][ks 0..1] 1KB chunks,
// frag-linear (lane*16) -> conflict-free ds_read_b128.
__global__ __launch_bounds__(512, 2) void gemm_i8_reg(
    const u64* __restrict__ bits, const char* __restrict__ limbs,
    float* __restrict__ out) {
    __shared__ __align__(16) char lds[2][32768];   // 64 KB

    const int tid  = threadIdx.x;
    const int lane = tid & 63;
    const int w    = tid >> 6;        // 0..7
    const int l31  = lane & 31;
    const int lh   = lane >> 5;       // k-half-of-half select
    const int bn   = blockIdx.x;      // 0..31 (32-col n panel)
    const int bm   = blockIdx.y;      // 0..31 (512-row m panel)

    v16i acc[2][4] = {};              // [m-tile][limb]

    // staging: wave w stages chunks id = w*4+j ; id = kk*8 + lb*2 + ks
    const char* gB[4];
    int ldsoff[4];
    #pragma unroll
    for (int j = 0; j < 4; ++j) {
        const int id = w * 4 + j;
        const int ks = id & 1, lb = (id >> 1) & 3, kk = id >> 3;
        gB[j] = limbs + (size_t)lb * (1 << 20) +
                (size_t)(bn * 32 + l31) * 1024 +
                (size_t)(kk * 64 + ks * 32 + lh * 16);
        ldsoff[j] = id * 1024;
    }

    // A bit rows for this wave's two m-tiles (u64 words, 16 per row)
    const u64* aRow0 = bits + (size_t)(bm * 512 + w * 64 + l31) * 16;
    const u64* aRow1 = aRow0 + 32 * 16;

    // prologue: stage half-K chunk 0 into buffer 0
    char* rb = lds[0];
    char* wbuf = lds[1];
    #pragma unroll
    for (int j = 0; j < 4; ++j) gload_lds16(gB[j], rb + ldsoff[j]);
    __syncthreads();

    for (int c = 0; c < 4; ++c) {     // 4 half-K chunks of 4 K-steps
        if (c < 3) {
            #pragma unroll
            for (int j = 0; j < 4; ++j)
                gload_lds16(gB[j] + (c + 1) * 256, wbuf + ldsoff[j]);
        }
        #pragma unroll
        for (int kk = 0; kk < 4; ++kk) {
            const int kw = c * 4 + kk;        // u64-word index within A row
            const u64 w0 = aRow0[kw];
            const u64 w1 = aRow1[kw];
            #pragma unroll
            for (int ks = 0; ks < 2; ++ks) {
                const v4i a0 = expand16((u32)(w0 >> (ks * 32 + lh * 16)) & 0xffffu);
                const v4i a1 = expand16((u32)(w1 >> (ks * 32 + lh * 16)) & 0xffffu);
                #pragma unroll
                for (int lb = 0; lb < 4; ++lb) {
                    const v4i b = *(const v4i*)(rb + ((kk * 4 + lb) * 2 + ks) * 1024 + lane * 16);
                    acc[0][lb] = __builtin_amdgcn_mfma_i32_32x32x32_i8(a0, b, acc[0][lb], 0, 0, 0);
                    acc[1][lb] = __builtin_amdgcn_mfma_i32_32x32x32_i8(a1, b, acc[1][lb], 0, 0, 0);
                }
            }
        }
        __syncthreads();
        char* t2 = rb; rb = wbuf; wbuf = t2;
    }

    // epilogue: combine limbs in fp64 (exact), one f32 rounding, store
    const int n = bn * 32 + l31;
    #pragma unroll
    for (int i = 0; i < 2; ++i) {
        #pragma unroll
        for (int r = 0; r < 16; ++r) {
            const double s = (double)acc[i][0][r] + 256.0 * (double)acc[i][1][r] +
                             65536.0 * (double)acc[i][2][r] +
                             16777216.0 * (double)acc[i][3][r];
            const float cur = (float)(s * 2.9103830456733704e-11);  // * 2^-35
            const int row = (r & 3) + 8 * (r >> 2) + 4 * lh;
            const int m = bm * 512 + w * 64 + i * 32 + row;
            out[(size_t)m * N_DIM + n] = cur;
        }
    }
}

// ---------------- LIF scan, fp64 state, depth-8 prefetch ring --------------
__global__ __launch_bounds__(256) void lif_scan3(float* __restrict__ buf) {
    const int gid = blockIdx.x * 256 + threadIdx.x;   // 0..65535
    float c[8];
    #pragma unroll
    for (int q = 0; q < 8; ++q) c[q] = buf[(size_t)q * PLANE + gid];
    double v = 0.0;
    for (int t = 0; t < T_STEPS; t += 8) {
        #pragma unroll
        for (int q = 0; q < 8; ++q) {
            const double cd = (double)c[q];
            v = v + (cd - v) * 0.5;
            const bool s = (v >= 1.0);
            buf[(size_t)(t + q) * PLANE + gid] = s ? 1.0f : 0.0f;
            v = s ? 0.0 : v;
            const int tn = t + q + 8;
            if (tn < T_STEPS) c[q] = buf[(size_t)tn * PLANE + gid];
        }
    }
}

// ---------------- fallback: round-1 fp64 GEMM (proven) ---------------------
__global__ __launch_bounds__(256) void lif_gemm_fp64(
    const float* __restrict__ X, const float* __restrict__ W,
    float* __restrict__ out) {
    __shared__ float As[64][68];
    __shared__ float Bs[64][68];
    const int tid = threadIdx.x;
    const int bn = blockIdx.x, bm = blockIdx.y;
    const int tn4 = tid & 15, tm4 = tid >> 4;
    double acc[4][4] = {};
    const int lrow = tid >> 2, lc4 = tid & 3;
    const float* Abase = X + (size_t)(bm * 64 + lrow) * K_DIM;
    const float* Bbase = W + (size_t)(bn * 64 + lrow) * K_DIM;
    for (int k0 = 0; k0 < K_DIM; k0 += 64) {
        #pragma unroll
        for (int j = 0; j < 4; ++j) {
            const int c = lc4 + 4 * j;
            float4 a = *reinterpret_cast<const float4*>(Abase + k0 + 4 * c);
            float4 b = *reinterpret_cast<const float4*>(Bbase + k0 + 4 * c);
            As[4*c+0][lrow] = a.x; As[4*c+1][lrow] = a.y;
            As[4*c+2][lrow] = a.z; As[4*c+3][lrow] = a.w;
            Bs[4*c+0][lrow] = b.x; Bs[4*c+1][lrow] = b.y;
            Bs[4*c+2][lrow] = b.z; Bs[4*c+3][lrow] = b.w;
        }
        __syncthreads();
        #pragma unroll 8
        for (int k = 0; k < 64; ++k) {
            float4 a4 = *reinterpret_cast<const float4*>(&As[k][tm4 * 4]);
            float4 b4 = *reinterpret_cast<const float4*>(&Bs[k][tn4 * 4]);
            const double ad[4] = {(double)a4.x, (double)a4.y, (double)a4.z, (double)a4.w};
            const double bd[4] = {(double)b4.x, (double)b4.y, (double)b4.z, (double)b4.w};
            #pragma unroll
            for (int i = 0; i < 4; ++i)
                #pragma unroll
                for (int j = 0; j < 4; ++j)
                    acc[i][j] = fma(ad[i], bd[j], acc[i][j]);
        }
        __syncthreads();
    }
    #pragma unroll
    for (int i = 0; i < 4; ++i) {
        const int m = bm * 64 + tm4 * 4 + i;
        float4 o;
        o.x = (float)acc[i][0]; o.y = (float)acc[i][1];
        o.z = (float)acc[i][2]; o.w = (float)acc[i][3];
        *reinterpret_cast<float4*>(out + (size_t)m * N_DIM + bn * 64 + tn4 * 4) = o;
    }
}

extern "C" void kernel_launch(void* const* d_in, const int* in_sizes, int n_in,
                              void* d_out, int out_size, void* d_ws, size_t ws_size,
                              hipStream_t stream) {
    const float* X = (const float*)d_in[0];
    const float* W = (const float*)d_in[1];
    float* out = (float*)d_out;

    if (ws_size >= (size_t)WS_NEEDED) {
        char* ws = (char*)d_ws;
        u64* bits = (u64*)ws;
        char* limbs = ws + WS_LIMB_OFF;
        prep_bits<<<M_DIM * K_DIM / 256, 256, 0, stream>>>(X, bits);
        prep_limbs<<<N_DIM * K_DIM / 256, 256, 0, stream>>>(W, limbs);
        dim3 grid(N_DIM / 32, M_DIM / 512);   // (32, 32)
        gemm_i8_reg<<<grid, 512, 0, stream>>>(bits, limbs, out);
    } else {
        dim3 grid(N_DIM / 64, M_DIM / 64);
        lif_gemm_fp64<<<grid, 256, 0, stream>>>(X, W, out);
    }
    lif_scan3<<<PLANE / 256, 256, 0, stream>>>(out);
}

// Round 4
// 117.929 us; speedup vs baseline: 6.7978x; 1.1519x over previous
//
#include <hip/hip_runtime.h>
#include <stdint.h>

// LIF SNN: cur = X @ W^T then LIF scan. T=256,B=64,F=1024 -> M=16384,N=K=1024.
// EXACT integer GEMM: W quantized at 2^-35 -> 4 signed i8 limbs,
// mfma_i32_32x32x32_i8 (exact i32 acc), fp64 limb combine (exact), one f32
// rounding -> decision-identical to exact fp64 (absmax 0.0, rounds 1-3).
//
// Round 4: 256-thr blocks (4 waves), wave tile 64m x 32n x 4 limbs, so TWO
// independent blocks co-reside per CU (barriers desynchronized -> one block's
// MFMA covers the other's staging drain). Chunk = 256k (32KB B panel, double
// buffered, 5 barriers/block). A bit-words double-buffered in registers.
// Nibble->i8x4 expansion via (x*0x204081)&0x01010101 (v_mul_u32_u24, 3 ops).

#define T_STEPS 256
#define M_DIM 16384
#define N_DIM 1024
#define K_DIM 1024
#define PLANE 65536   // B*F

typedef int v4i  __attribute__((ext_vector_type(4)));
typedef int v16i __attribute__((ext_vector_type(16)));
typedef unsigned int u32;
typedef unsigned long long u64;

#define WS_BITS_SZ  (M_DIM * 128)                 // X as bits: 2 MB
#define WS_LIMB_OFF WS_BITS_SZ                    // 4 i8 planes x 1 MB
#define WS_NEEDED   (WS_BITS_SZ + 4 * (1 << 20))  // 6 MB

__device__ __forceinline__ void gload_lds16(const void* g, void* l) {
    __builtin_amdgcn_global_load_lds(
        (const __attribute__((address_space(1))) u32*)g,
        (__attribute__((address_space(3))) u32*)l, 16, 0, 0);
}

// expand 16 k-bits -> 16 i8 bytes (0/1) in 4 u32; 3 VALU per nibble
__device__ __forceinline__ v4i expand16(u32 sb) {
    v4i r;
    #pragma unroll
    for (int q = 0; q < 4; ++q) {
        const u32 x = (sb >> (4 * q)) & 0xFu;          // < 2^4
        r[q] = (int)((x * 0x00204081u) & 0x01010101u); // 24-bit mul spread
    }
    return r;
}

// ---------------- prep: pack X (0.0/1.0) into bits -------------------------
__global__ __launch_bounds__(256) void prep_bits(const float* __restrict__ X,
                                                 u64* __restrict__ bits) {
    const int gid = blockIdx.x * 256 + threadIdx.x;
    const float x = X[gid];
    const u64 m = __ballot(x != 0.0f);
    if ((threadIdx.x & 63) == 0) bits[gid >> 6] = m;
}

// ---------------- prep: W -> 4 signed i8 limb planes at scale 2^-35 --------
__global__ __launch_bounds__(256) void prep_limbs(const float* __restrict__ W,
                                                  char* __restrict__ limbs) {
    const int gid = blockIdx.x * 256 + threadIdx.x;   // 0..2^20-1
    const double d = (double)W[gid] * 34359738368.0;  // * 2^35, exact
    long long k = llrint(d);                          // |k| <= 2^30
    const int8_t l0 = (int8_t)k; k = (k - l0) >> 8;   // exact balanced digits
    const int8_t l1 = (int8_t)k; k = (k - l1) >> 8;
    const int8_t l2 = (int8_t)k; k = (k - l2) >> 8;
    const int8_t l3 = (int8_t)k;
    limbs[gid]                 = (char)l0;
    limbs[gid + (1 << 20)]     = (char)l1;
    limbs[gid + 2 * (1 << 20)] = (char)l2;
    limbs[gid + 3 * (1 << 20)] = (char)l3;
}

// ---------------- i8 MFMA GEMM: 4-wave blocks, 2 blocks/CU -----------------
// Grid (32 n-panels, 64 m-panels). Wave w owns rows [bm*256+w*64, +64) as two
// 32-row m-tiles; all waves share the 32-col B panel.
// LDS: 2 buffers x 32KB; buffer = 32 chunks of 1KB, id = ks32*4 + lb,
// frag-linear (lane*16) -> conflict-free ds_read_b128.
__global__ __launch_bounds__(256, 2) void gemm_i8_reg2(
    const u64* __restrict__ bits, const char* __restrict__ limbs,
    float* __restrict__ out) {
    __shared__ __align__(16) char lds[2][32768];   // 64 KB

    const int tid  = threadIdx.x;
    const int lane = tid & 63;
    const int w    = tid >> 6;        // 0..3
    const int l31  = lane & 31;
    const int lh   = lane >> 5;
    const int bn   = blockIdx.x;      // 0..31
    const int bm   = blockIdx.y;      // 0..63

    v16i acc[2][4] = {};              // [m-tile][limb]

    // staging: wave w stages ids w*8+j, j=0..7 ; id = ks32*4 + lb
    const char* gB[8];
    #pragma unroll
    for (int j = 0; j < 8; ++j) {
        const int id = w * 8 + j;
        const int lb = id & 3, ks32 = id >> 2;
        gB[j] = limbs + (size_t)lb * (1 << 20) +
                (size_t)(bn * 32 + l31) * 1024 +
                (size_t)(ks32 * 32 + lh * 16);
    }
    const int ldsbase = w * 8192 + lane * 16;   // ids w*8.. packed consecutively

    // A bit rows (u64 words, 16 per row) for this wave's two m-tiles
    const u64* aRow0 = bits + (size_t)(bm * 256 + w * 64 + l31) * 16;
    const u64* aRow1 = aRow0 + 32 * 16;

    // prologue: stage chunk 0, load A words for chunk 0
    u64 aw0[4], aw1[4], an0[4], an1[4];
    #pragma unroll
    for (int j = 0; j < 8; ++j) gload_lds16(gB[j], lds[0] + ldsbase + j * 1024);
    #pragma unroll
    for (int q = 0; q < 4; ++q) { aw0[q] = aRow0[q]; aw1[q] = aRow1[q]; }
    __syncthreads();

    char* rb = lds[0];
    char* wb = lds[1];
    for (int c = 0; c < 4; ++c) {     // 4 chunks of 256 k
        if (c < 3) {
            #pragma unroll
            for (int j = 0; j < 8; ++j)
                gload_lds16(gB[j] + (c + 1) * 256, wb + ldsbase + j * 1024);
            #pragma unroll
            for (int q = 0; q < 4; ++q) {
                an0[q] = aRow0[(c + 1) * 4 + q];
                an1[q] = aRow1[(c + 1) * 4 + q];
            }
        }
        #pragma unroll
        for (int ks = 0; ks < 8; ++ks) {          // 8 k-steps of 32
            const int sh = (ks & 1) * 32 + lh * 16;
            const v4i a0 = expand16((u32)(aw0[ks >> 1] >> sh) & 0xffffu);
            const v4i a1 = expand16((u32)(aw1[ks >> 1] >> sh) & 0xffffu);
            #pragma unroll
            for (int lb = 0; lb < 4; ++lb) {
                const v4i b = *(const v4i*)(rb + (ks * 4 + lb) * 1024 + lane * 16);
                acc[0][lb] = __builtin_amdgcn_mfma_i32_32x32x32_i8(a0, b, acc[0][lb], 0, 0, 0);
                acc[1][lb] = __builtin_amdgcn_mfma_i32_32x32x32_i8(a1, b, acc[1][lb], 0, 0, 0);
            }
        }
        __syncthreads();
        char* t2 = rb; rb = wb; wb = t2;
        #pragma unroll
        for (int q = 0; q < 4; ++q) { aw0[q] = an0[q]; aw1[q] = an1[q]; }
    }

    // epilogue: combine limbs in fp64 (exact), one f32 rounding, store
    const int n = bn * 32 + l31;
    #pragma unroll
    for (int i = 0; i < 2; ++i) {
        #pragma unroll
        for (int r = 0; r < 16; ++r) {
            const double s = (double)acc[i][0][r] + 256.0 * (double)acc[i][1][r] +
                             65536.0 * (double)acc[i][2][r] +
                             16777216.0 * (double)acc[i][3][r];
            const float cur = (float)(s * 2.9103830456733704e-11);  // * 2^-35
            const int row = (r & 3) + 8 * (r >> 2) + 4 * lh;
            const int m = bm * 256 + w * 64 + i * 32 + row;
            out[(size_t)m * N_DIM + n] = cur;
        }
    }
}

// ---------------- LIF scan, fp64 state, depth-16 prefetch ring -------------
__global__ __launch_bounds__(256) void lif_scan4(float* __restrict__ buf) {
    const int gid = blockIdx.x * 256 + threadIdx.x;   // 0..65535
    float c[16];
    #pragma unroll
    for (int q = 0; q < 16; ++q) c[q] = buf[(size_t)q * PLANE + gid];
    double v = 0.0;
    for (int t = 0; t < T_STEPS; t += 16) {
        #pragma unroll
        for (int q = 0; q < 16; ++q) {
            const double cd = (double)c[q];
            v = v + (cd - v) * 0.5;
            const bool s = (v >= 1.0);
            buf[(size_t)(t + q) * PLANE + gid] = s ? 1.0f : 0.0f;
            v = s ? 0.0 : v;
            const int tn = t + q + 16;
            if (tn < T_STEPS) c[q] = buf[(size_t)tn * PLANE + gid];
        }
    }
}

// ---------------- fallback: round-1 fp64 GEMM (proven) ---------------------
__global__ __launch_bounds__(256) void lif_gemm_fp64(
    const float* __restrict__ X, const float* __restrict__ W,
    float* __restrict__ out) {
    __shared__ float As[64][68];
    __shared__ float Bs[64][68];
    const int tid = threadIdx.x;
    const int bn = blockIdx.x, bm = blockIdx.y;
    const int tn4 = tid & 15, tm4 = tid >> 4;
    double acc[4][4] = {};
    const int lrow = tid >> 2, lc4 = tid & 3;
    const float* Abase = X + (size_t)(bm * 64 + lrow) * K_DIM;
    const float* Bbase = W + (size_t)(bn * 64 + lrow) * K_DIM;
    for (int k0 = 0; k0 < K_DIM; k0 += 64) {
        #pragma unroll
        for (int j = 0; j < 4; ++j) {
            const int c = lc4 + 4 * j;
            float4 a = *reinterpret_cast<const float4*>(Abase + k0 + 4 * c);
            float4 b = *reinterpret_cast<const float4*>(Bbase + k0 + 4 * c);
            As[4*c+0][lrow] = a.x; As[4*c+1][lrow] = a.y;
            As[4*c+2][lrow] = a.z; As[4*c+3][lrow] = a.w;
            Bs[4*c+0][lrow] = b.x; Bs[4*c+1][lrow] = b.y;
            Bs[4*c+2][lrow] = b.z; Bs[4*c+3][lrow] = b.w;
        }
        __syncthreads();
        #pragma unroll 8
        for (int k = 0; k < 64; ++k) {
            float4 a4 = *reinterpret_cast<const float4*>(&As[k][tm4 * 4]);
            float4 b4 = *reinterpret_cast<const float4*>(&Bs[k][tn4 * 4]);
            const double ad[4] = {(double)a4.x, (double)a4.y, (double)a4.z, (double)a4.w};
            const double bd[4] = {(double)b4.x, (double)b4.y, (double)b4.z, (double)b4.w};
            #pragma unroll
            for (int i = 0; i < 4; ++i)
                #pragma unroll
                for (int j = 0; j < 4; ++j)
                    acc[i][j] = fma(ad[i], bd[j], acc[i][j]);
        }
        __syncthreads();
    }
    #pragma unroll
    for (int i = 0; i < 4; ++i) {
        const int m = bm * 64 + tm4 * 4 + i;
        float4 o;
        o.x = (float)acc[i][0]; o.y = (float)acc[i][1];
        o.z = (float)acc[i][2]; o.w = (float)acc[i][3];
        *reinterpret_cast<float4*>(out + (size_t)m * N_DIM + bn * 64 + tn4 * 4) = o;
    }
}

extern "C" void kernel_launch(void* const* d_in, const int* in_sizes, int n_in,
                              void* d_out, int out_size, void* d_ws, size_t ws_size,
                              hipStream_t stream) {
    const float* X = (const float*)d_in[0];
    const float* W = (const float*)d_in[1];
    float* out = (float*)d_out;

    if (ws_size >= (size_t)WS_NEEDED) {
        char* ws = (char*)d_ws;
        u64* bits = (u64*)ws;
        char* limbs = ws + WS_LIMB_OFF;
        prep_bits<<<M_DIM * K_DIM / 256, 256, 0, stream>>>(X, bits);
        prep_limbs<<<N_DIM * K_DIM / 256, 256, 0, stream>>>(W, limbs);
        dim3 grid(N_DIM / 32, M_DIM / 256);   // (32, 64)
        gemm_i8_reg2<<<grid, 256, 0, stream>>>(bits, limbs, out);
    } else {
        dim3 grid(N_DIM / 64, M_DIM / 64);
        lif_gemm_fp64<<<grid, 256, 0, stream>>>(X, W, out);
    }
    lif_scan4<<<PLANE / 256, 256, 0, stream>>>(out);
}